// Round 10
// baseline (2332.043 us; speedup 1.0000x reference)
//
#include <hip/hip_runtime.h>

// FusedMoEIntegrator — MI355X/gfx950, round 10.
// Changes vs round 9:
//  - exp2r: register diet for 3 waves/SIMD: ABCD -> vt/gv direct accumulation
//    (-32 regs), MFMA split into two cf-halves (acc 12 -> 6, -24 regs), toks
//    from LDS at combine. Live ~140 -> __launch_bounds__(256,3) cap 170, safe.
//  - exp1 reverted to per-path blocks (grid (3,NDESC)=960): r5 vs r6 evidence
//    shows the 320-block merged exp1t cost ~100-140us (1.25 blocks/CU).

#define TOK   16384
#define DDIM  1024
#define NEXP  8
#define DTC   0.1f
#define NDESC 320    // max 64-row tiles: 256 + 28 partials
#define GPAD  20480  // padded permuted rows

using f32x4 = __attribute__((ext_vector_type(4))) float;
using bfv8  = __attribute__((ext_vector_type(8))) short;

__device__ __forceinline__ unsigned short f2bf(float x){
  unsigned u = __builtin_bit_cast(unsigned, x);
  u += 0x7fffu + ((u >> 16) & 1u);
  return (unsigned short)(u >> 16);
}
__device__ __forceinline__ float bf2f(unsigned short h){
  return __builtin_bit_cast(float, ((unsigned)h) << 16);
}
__device__ __forceinline__ float sigmf(float x){ return 1.0f/(1.0f+__expf(-x)); }
__device__ __forceinline__ float geluf(float x){
  float u = 1.595769122f * __builtin_fmaf(0.044715f*x*x, x, x);
  return x * sigmf(u);
}
__device__ __forceinline__ float softpf(float x){
  return fmaxf(x, 0.0f) + __logf(1.0f + __expf(-fabsf(x)));
}
__device__ __forceinline__ f32x4 mfma16(bfv8 a, bfv8 b, f32x4 c){
  return __builtin_amdgcn_mfma_f32_16x16x32_bf16(a, b, c, 0, 0, 0);
}
typedef __attribute__((address_space(1))) const void gvoid_t;
typedef __attribute__((address_space(3))) void svoid_t;
__device__ __forceinline__ void gload16(const void* g, void* l){
  __builtin_amdgcn_global_load_lds((gvoid_t*)g, (svoid_t*)l, 16, 0, 0);
}

// -------- transpose+cast -----------------------------------------------------
__global__ __launch_bounds__(256) void transpose_cast(
    const float* __restrict__ src, unsigned short* __restrict__ dst, int R, int C)
{
  __shared__ float tile[32][33];
  size_t bo = (size_t)blockIdx.z * R * C;
  const float* s = src + bo;
  unsigned short* d = dst + bo;
  int c0 = blockIdx.x * 32, r0 = blockIdx.y * 32;
  int tx = threadIdx.x, ty = threadIdx.y;
  #pragma unroll
  for (int j = 0; j < 4; j++)
    tile[ty + 8*j][tx] = s[(size_t)(r0 + ty + 8*j) * C + c0 + tx];
  __syncthreads();
  #pragma unroll
  for (int j = 0; j < 4; j++)
    d[(size_t)(c0 + ty + 8*j) * R + r0 + tx] = f2bf(tile[tx][ty + 8*j]);
}

// -------- xinit: xaccB = bf16(x) (token order, router A) ---------------------
__global__ __launch_bounds__(256) void xinit_k(
    const float* __restrict__ xf, unsigned short* __restrict__ xb)
{
  const int n = TOK * 256;
  for (int i = blockIdx.x * 256 + threadIdx.x; i < n; i += gridDim.x * 256) {
    float4 f = ((const float4*)xf)[i];
    ushort4 u = {f2bf(f.x), f2bf(f.y), f2bf(f.z), f2bf(f.w)};
    ((ushort4*)xb)[i] = u;
  }
}

// -------- ctx build (permuted rows; init only) -------------------------------
__global__ __launch_bounds__(256) void ctxb_k(
    const float* __restrict__ xf, const int* __restrict__ tokmap,
    unsigned short* __restrict__ ctx)
{
  const int g = blockIdx.x, tid = threadIdx.x;
  const int t = tokmap[g];
  if (tid < 128) {
    uint4 o4 = {0,0,0,0};
    if (t >= 0) {
      const float4* s = (const float4*)(xf + (size_t)t * 1024) + tid * 2;
      float4 f0 = s[0], f1 = s[1];
      unsigned short tmp[8] = {f2bf(f0.x), f2bf(f0.y), f2bf(f0.z), f2bf(f0.w),
                               f2bf(f1.x), f2bf(f1.y), f2bf(f1.z), f2bf(f1.w)};
      o4 = *(uint4*)tmp;
    }
    *(uint4*)&ctx[(size_t)g * 2048 + tid * 8] = o4;
  } else {
    *(uint4*)&ctx[(size_t)g * 2048 + 1024 + (tid - 128) * 8] = uint4{0,0,0,0};
  }
}

// -------- main GEMM ----------------------------------------------------------
template<int EPI>
__global__ __launch_bounds__(256) void gemm_k(
    const unsigned short* __restrict__ A, int lda,
    const unsigned short* __restrict__ BT,
    const float* __restrict__ bias, const float* __restrict__ bias2,
    int Kd, int N,
    unsigned short* __restrict__ obf, unsigned short* __restrict__ obf2,
    const float* __restrict__ halt, const float* __restrict__ iw,
    float* __restrict__ integ, unsigned short* __restrict__ ctxX,
    const int* __restrict__ pf)
{
  __shared__ unsigned short As[128][64];
  __shared__ unsigned short Bs[128][64];
  const int total = gridDim.x * gridDim.y;
  const int bid = blockIdx.y * gridDim.x + blockIdx.x;
  const int swz = (bid & 7) * (total >> 3) + (bid >> 3);
  const int bx = swz % gridDim.x, by = swz / gridDim.x;

  const int tid  = threadIdx.x, lane = tid & 63, w = tid >> 6;
  const int wm   = w >> 1, wn = w & 1;
  const int gm0  = by * 128, gn0 = bx * 128;
  const int r8   = lane >> 3;
  const int sseg = (lane & 7) ^ r8;

  const unsigned short* aga[4];
  const unsigned short* bga[4];
  #pragma unroll
  for (int c = 0; c < 4; c++) {
    aga[c] = A  + (size_t)(gm0 + w*32 + c*8 + r8) * lda + sseg*8;
    bga[c] = BT + (size_t)(gn0 + w*32 + c*8 + r8) * Kd  + sseg*8;
  }

  f32x4 acc[4][4];
  #pragma unroll
  for (int i = 0; i < 4; i++)
    #pragma unroll
    for (int j = 0; j < 4; j++)
      acc[i][j] = f32x4{0.f,0.f,0.f,0.f};

  const int xr = (lane & 7) << 3;
  for (int k0 = 0; k0 < Kd; k0 += 64) {
    #pragma unroll
    for (int c = 0; c < 4; c++) gload16(aga[c] + k0, &As[w*32 + c*8][0]);
    #pragma unroll
    for (int c = 0; c < 4; c++) gload16(bga[c] + k0, &Bs[w*32 + c*8][0]);
    __syncthreads();
    #pragma unroll
    for (int kk = 0; kk < 64; kk += 32) {
      const int kof = kk + ((lane >> 4) << 3);
      bfv8 a[4], b[4];
      #pragma unroll
      for (int mf = 0; mf < 4; mf++)
        a[mf] = *(const bfv8*)&As[wm*64 + mf*16 + (lane & 15)][kof ^ xr];
      #pragma unroll
      for (int nf = 0; nf < 4; nf++)
        b[nf] = *(const bfv8*)&Bs[wn*64 + nf*16 + (lane & 15)][kof ^ xr];
      #pragma unroll
      for (int mf = 0; mf < 4; mf++)
        #pragma unroll
        for (int nf = 0; nf < 4; nf++)
          acc[mf][nf] = mfma16(a[mf], b[nf], acc[mf][nf]);
    }
    __syncthreads();
  }

  #pragma unroll
  for (int mf = 0; mf < 4; mf++) {
    #pragma unroll
    for (int nf = 0; nf < 4; nf++) {
      int col = gn0 + wn*64 + nf*16 + (lane & 15);
      float bc;
      if (EPI == 2) bc = (col < 2048) ? bias[col] : bias2[col - 2048];
      else          bc = bias[col];
      #pragma unroll
      for (int r = 0; r < 4; r++) {
        int row = gm0 + wm*64 + mf*16 + ((lane >> 4) << 2) + r;
        float v = acc[mf][nf][r] + bc;
        if (EPI == 0) {
          obf[(size_t)row * N + col] = f2bf(geluf(v));
        } else if (EPI == 2) {
          if (col < 2048) obf [(size_t)row * 2048 + col]         = f2bf(geluf(v));
          else            obf2[(size_t)row * 256 + (col - 2048)] = f2bf(geluf(v));
        } else {
          size_t ix = (size_t)row * DDIM + col;
          float nv = integ[ix] + halt[row] * v * iw[col];
          integ[ix] = nv;
          if (ctxX) ctxX[(size_t)pf[row] * 2048 + col] = f2bf(nv);
        }
      }
    }
  }
}

// -------- router second stage ------------------------------------------------
__global__ __launch_bounds__(256) void router_k(
    const unsigned short* __restrict__ h1, const float* __restrict__ w_r2,
    const float* __restrict__ b_r2, int* __restrict__ topi, float* __restrict__ topw)
{
  int t = blockIdx.x * 4 + (threadIdx.x >> 6);
  int lane = threadIdx.x & 63;
  const unsigned short* hp = h1 + (size_t)t * 256 + lane * 4;
  float hv[4];
  #pragma unroll
  for (int j = 0; j < 4; j++) hv[j] = bf2f(hp[j]);
  float acc[8];
  #pragma unroll
  for (int e = 0; e < 8; e++) acc[e] = 0.f;
  #pragma unroll
  for (int j = 0; j < 4; j++) {
    const float* wr = w_r2 + (size_t)(lane*4 + j) * 8;
    #pragma unroll
    for (int e = 0; e < 8; e++) acc[e] += hv[j] * wr[e];
  }
  #pragma unroll
  for (int off = 32; off > 0; off >>= 1)
    #pragma unroll
    for (int e = 0; e < 8; e++) acc[e] += __shfl_xor(acc[e], off);
  if (lane == 0) {
    float lg[8];
    #pragma unroll
    for (int e = 0; e < 8; e++) lg[e] = acc[e] + b_r2[e];
    int i0 = 0; float m0 = lg[0];
    #pragma unroll
    for (int e = 1; e < 8; e++) if (lg[e] > m0) { m0 = lg[e]; i0 = e; }
    int i1 = -1; float m1 = -3.4e38f;
    #pragma unroll
    for (int e = 0; e < 8; e++) if (e != i0 && lg[e] > m1) { m1 = lg[e]; i1 = e; }
    float w0 = 1.0f / (1.0f + expf(m1 - m0));
    topi[t*2] = i0; topi[t*2+1] = i1;
    topw[t*2] = w0; topw[t*2+1] = 1.0f - w0;
  }
}

// -------- halt gate second stage ---------------------------------------------
__global__ __launch_bounds__(256) void haltgate_k(
    const unsigned short* __restrict__ h1, const float* __restrict__ w_h2,
    const float* __restrict__ b_h2, float* __restrict__ halt)
{
  int t = blockIdx.x * 4 + (threadIdx.x >> 6);
  int lane = threadIdx.x & 63;
  const unsigned short* hp = h1 + (size_t)t * 256 + lane * 4;
  float s = 0.f;
  #pragma unroll
  for (int j = 0; j < 4; j++) s += bf2f(hp[j]) * w_h2[lane*4 + j];
  #pragma unroll
  for (int off = 32; off > 0; off >>= 1) s += __shfl_xor(s, off);
  if (lane == 0) halt[t] = sigmf(s + b_h2[0]);
}

// -------- pair bucketing -----------------------------------------------------
__global__ __launch_bounds__(256) void pairb_k(
    const int* __restrict__ topi, const float* __restrict__ topw,
    int* __restrict__ cnt, int* __restrict__ plist, float* __restrict__ wA)
{
  int t = blockIdx.x * 256 + threadIdx.x;
  int a = topi[2*t], b = topi[2*t+1];
  float wa = topw[2*t];
  if (a > b) { int tmp = a; a = b; b = tmp; wa = 1.0f - wa; }
  int pid = a * 8 + b;
  int pos = atomicAdd(&cnt[pid], 1);
  plist[pid * TOK + pos] = t;
  wA[t] = wa;
}

// desc: {pid, rbt (64-aligned permuted row base), cnt, 0}
__global__ void desc_k(const int* __restrict__ cnt, int4* __restrict__ desc,
                       int* __restrict__ ndesc, int* __restrict__ pbase)
{
  if (threadIdx.x == 0 && blockIdx.x == 0) {
    int nt = 0, rb = 0;
    for (int p = 0; p < 64; p++) {
      pbase[p] = rb;
      int c = cnt[p];
      for (int o = 0; o < c; o += 64) {
        int rem = c - o; if (rem > 64) rem = 64;
        desc[nt] = make_int4(p, rb + o, rem, 0);
        nt++;
      }
      rb += (c + 63) & ~63;
    }
    ndesc[0] = nt;
  }
}

// pmap: tokmap[g] = token, pf[token] = g
__global__ __launch_bounds__(256) void pmap_k(
    const int* __restrict__ cnt, const int* __restrict__ pbase,
    const int* __restrict__ plist, int* __restrict__ tokmap, int* __restrict__ pf)
{
  int pid = blockIdx.x;
  int pos = blockIdx.y * 256 + threadIdx.x;
  if (pos < cnt[pid]) {
    int t = plist[pid * TOK + pos];
    int g = pbase[pid] + pos;
    tokmap[g] = t;
    pf[t] = g;
  }
}

// -------- exp1p: ONE path per block; hidden = gelu(ctx @ w1 + b1) ------------
// grid (3, NDESC): same-tile paths adjacent (L2 reuse of the A rows).
__global__ __launch_bounds__(256) void exp1p_k(
    const unsigned short* __restrict__ ctx,
    const int4* __restrict__ desc, const int* __restrict__ ndesc,
    const unsigned short* __restrict__ ew1T, const float* __restrict__ eb1,
    const unsigned short* __restrict__ ws1T, const float* __restrict__ bs1,
    unsigned short* __restrict__ hiddenG)
{
  __shared__ unsigned short As[64][64];
  __shared__ unsigned short Bs[64][64];
  const int path = blockIdx.x, dx = blockIdx.y;
  if (dx >= ndesc[0]) return;
  int4 dd = desc[dx];
  const int pid = dd.x, rbt = dd.y;
  const int ep = (path == 0) ? (pid >> 3) : (pid & 7);
  const unsigned short* w1 = (path < 2) ? ew1T + (size_t)ep * 64 * 2048 : ws1T;
  const float* b1 = (path < 2) ? eb1 + ep * 64 : bs1;
  const int tid = threadIdx.x, lane = tid & 63, w = tid >> 6;

  const int arow = w*8 + (lane >> 3);
  const int sseg = (lane & 7) ^ (lane >> 3);
  const unsigned short* asrc[2];
  const unsigned short* bsrc[2];
  #pragma unroll
  for (int q = 0; q < 2; q++) {
    asrc[q] = ctx + (size_t)(rbt + q*32 + arow) * 2048 + sseg * 8;
    bsrc[q] = w1  + (size_t)(q*32 + arow) * 2048 + sseg * 8;
  }

  f32x4 acc[4];
  #pragma unroll
  for (int j = 0; j < 4; j++) acc[j] = f32x4{0.f,0.f,0.f,0.f};

  const int xr = (lane & 7) << 3;
  for (int k0 = 0; k0 < 2048; k0 += 64) {
    #pragma unroll
    for (int q = 0; q < 2; q++) gload16(asrc[q] + k0, &As[q*32 + w*8][0]);
    #pragma unroll
    for (int q = 0; q < 2; q++) gload16(bsrc[q] + k0, &Bs[q*32 + w*8][0]);
    __syncthreads();
    #pragma unroll
    for (int kk = 0; kk < 64; kk += 32) {
      const int kof = kk + ((lane >> 4) << 3);
      bfv8 a = *(const bfv8*)&As[w*16 + (lane & 15)][kof ^ xr];
      #pragma unroll
      for (int nf = 0; nf < 4; nf++) {
        bfv8 b = *(const bfv8*)&Bs[nf*16 + (lane & 15)][kof ^ xr];
        acc[nf] = mfma16(a, b, acc[nf]);
      }
    }
    __syncthreads();
  }

  #pragma unroll
  for (int nf = 0; nf < 4; nf++) {
    int col = nf*16 + (lane & 15);
    float bb = b1[col];
    #pragma unroll
    for (int r = 0; r < 4; r++) {
      int row = w*16 + ((lane >> 4) << 2) + r;
      hiddenG[(size_t)(3*rbt + path*64 + row) * 64 + col] =
          f2bf(geluf(acc[nf][r] + bb));
    }
  }
}

// -------- exp2r: pipelined 3-path GEMM + vt/gv accumulate + combine ----------
// grid (4, NDESC). One barrier/phase, W2 double-buffered, cf-split MFMA.
// Live regs ~140 -> (256,3) cap 170 is safe; 3 blocks/CU (LDS 149KB).
__global__ __launch_bounds__(256, 3) void exp2r_k(
    const unsigned short* __restrict__ hiddenG,
    const int4* __restrict__ desc, const int* __restrict__ ndesc,
    const int* __restrict__ tokmap, const float* __restrict__ wA,
    const unsigned short* __restrict__ ew2T, const float* __restrict__ eb2,
    const unsigned short* __restrict__ ws2T, const float* __restrict__ bs2,
    const float* __restrict__ swp, const float* __restrict__ mu,
    unsigned short* __restrict__ ctx, unsigned short* __restrict__ xaccB)
{
  __shared__ unsigned short W2s[2][192][64];   // 48KB double buffer
  __shared__ int   s_tok[64];
  __shared__ float s_w[64];
  const int zq = blockIdx.x, dx = blockIdx.y;
  if (dx >= ndesc[0]) return;
  int4 dd = desc[dx];
  const int pid = dd.x, rbt = dd.y, cnt = dd.z;
  const int e0 = pid >> 3, e1 = pid & 7;
  const int tid = threadIdx.x, lane = tid & 63, w = tid >> 6;
  const float sw  = sigmf(swp[0]);
  const float swc = 1.0f - sw;

  if (tid < 64) {
    int t = tokmap[rbt + tid]; if (t < 0) t = 0;
    s_tok[tid] = t; s_w[tid] = wA[t];
  }

  const unsigned short* w2b[3] = { ew2T + (size_t)e0*3072*64,
                                   ew2T + (size_t)e1*3072*64, ws2T };
  const float* b2b[3] = { eb2 + e0*3072, eb2 + e1*3072, bs2 };
  const int d0q  = zq * 256;
  const int srow = w*8 + (lane >> 3);
  const int sseg = (lane & 7) ^ (lane >> 3);
  const int xr   = (lane & 7) << 3;
  const int cr4  = (lane >> 4) << 2;
  const int arow = w*16 + (lane & 15);
  const int kof8 = (lane >> 4) << 3;

  // A-fragments straight from global (coalesced 16B reads, L2-hot)
  bfv8 afr[3][2];
  #pragma unroll
  for (int p = 0; p < 3; p++)
    #pragma unroll
    for (int kk = 0; kk < 2; kk++)
      afr[p][kk] = *(const bfv8*)&hiddenG[
          (size_t)(3*rbt + p*64 + arow) * 64 + kk*32 + kof8];

  auto STAGE = [&](int b, int dcq, int path) {
    const int d00 = d0q + dcq*64;
    const unsigned short* w2 = w2b[path];
    #pragma unroll
    for (int q = 0; q < 6; q++) {
      int row  = q*32 + srow;
      int grow = (row >> 6)*1024 + d00 + (row & 63);
      gload16(w2 + (size_t)grow*64 + sseg*8, &W2s[b][q*32 + w*8][0]);
    }
  };

  STAGE(0, 0, 0);              // prologue
  float wa4p[4];               // (1-sw) * wa  (premultiplied)
  float err[4][4], vv[4][4], muv4[4];
  float vt[4][4], gv[4][4];

  #pragma unroll
  for (int dcq = 0; dcq < 4; dcq++) {
    const int d00 = d0q + dcq*64;
    #pragma unroll
    for (int cf = 0; cf < 4; cf++)
      #pragma unroll
      for (int r = 0; r < 4; r++) { vt[cf][r] = 0.f; gv[cf][r] = 0.f; }
    #pragma unroll
    for (int path = 0; path < 3; path++) {
      const int ph = dcq*3 + path;
      __syncthreads();                       // gate: phase ph's stage landed
      if (ph == 0) {
        #pragma unroll
        for (int r = 0; r < 4; r++)
          wa4p[r] = swc * s_w[w*16 + cr4 + r];
        #pragma unroll
        for (int cf = 0; cf < 4; cf++) {
          int d = d00 + cf*16 + (lane & 15);
          muv4[cf] = mu[d];
          #pragma unroll
          for (int r = 0; r < 4; r++) {
            size_t g = (size_t)(rbt + w*16 + cr4 + r);
            err[cf][r] = bf2f(ctx[g*2048 + d]) - muv4[cf];
            vv[cf][r]  = bf2f(ctx[g*2048 + 1024 + d]);
          }
        }
      }
      if (ph < 11) {                          // next stage overlaps compute
        const int phn = ph + 1;
        STAGE(phn & 1, phn / 3, phn % 3);
      }
      const float* b2 = b2b[path];
      // cf-split: two halves of {al,be,ga} columns -> acc[6] each
      #pragma unroll
      for (int cfh = 0; cfh < 2; cfh++) {
        f32x4 acc[6];
        #pragma unroll
        for (int j = 0; j < 6; j++) acc[j] = f32x4{0.f,0.f,0.f,0.f};
        #pragma unroll
        for (int kk = 0; kk < 2; kk++) {
          const int kof = kk*32 + kof8;
          #pragma unroll
          for (int j = 0; j < 6; j++) {
            int nf = cfh*2 + (j & 1) + (j >> 1) * 4;
            bfv8 b = *(const bfv8*)&W2s[ph & 1][nf*16 + (lane & 15)][kof ^ xr];
            acc[j] = mfma16(afr[path][kk], b, acc[j]);
          }
        }
        #pragma unroll
        for (int cj = 0; cj < 2; cj++) {
          int cf = cfh*2 + cj;
          int d = d00 + cf*16 + (lane & 15);
          float ba = b2[d], bb = b2[1024 + d], bg = b2[2048 + d];
          #pragma unroll
          for (int r = 0; r < 4; r++) {
            float cw = (path == 0) ? wa4p[r]
                     : (path == 1) ? (swc - wa4p[r]) : sw;
            float al = sigmf(acc[cj][r] + ba);
            float be = softpf(acc[2 + cj][r] + bb);
            float ga = sigmf(acc[4 + cj][r] + bg);
            float vn = al * vv[cf][r] - be * err[cf][r];
            vt[cf][r] = __builtin_fmaf(cw, vn, vt[cf][r]);
            gv[cf][r] = __builtin_fmaf(cw, ga * vn, gv[cf][r]);
          }
        }
      }
    }
    // combine + write for this d-chunk
    #pragma unroll
    for (int cf = 0; cf < 4; cf++) {
      int d = d00 + cf*16 + (lane & 15);
      #pragma unroll
      for (int r = 0; r < 4; r++) {
        int row = w*16 + cr4 + r;
        size_t g = (size_t)(rbt + row);
        float xx = err[cf][r] + muv4[cf];
        if (row < cnt) {
          int tok = s_tok[row];
          xaccB[(size_t)tok*1024 + d] = f2bf(xx + DTC * gv[cf][r]);
          ctx[g*2048 + 1024 + d]      = f2bf(vt[cf][r]);
        }
      }
    }
    if (dcq < 3) {   // prefetch next d-chunk's err/vv (old regs consumed)
      const int dn = d00 + 64;
      #pragma unroll
      for (int cf = 0; cf < 4; cf++) {
        int d = dn + cf*16 + (lane & 15);
        muv4[cf] = mu[d];
        #pragma unroll
        for (int r = 0; r < 4; r++) {
          size_t g = (size_t)(rbt + w*16 + cr4 + r);
          err[cf][r] = bf2f(ctx[g*2048 + d]) - muv4[cf];
          vv[cf][r]  = bf2f(ctx[g*2048 + 1024 + d]);
        }
      }
    }
  }
}

// -----------------------------------------------------------------------------
extern "C" void kernel_launch(void* const* d_in, const int* in_sizes, int n_in,
                              void* d_out, int out_size, void* d_ws, size_t ws_size,
                              hipStream_t stream)
{
  const float* x    = (const float*)d_in[0];
  const float* w_r1 = (const float*)d_in[1];
  const float* b_r1 = (const float*)d_in[2];
  const float* w_r2 = (const float*)d_in[3];
  const float* b_r2 = (const float*)d_in[4];
  const float* w_h1 = (const float*)d_in[5];
  const float* b_h1 = (const float*)d_in[6];
  const float* w_h2 = (const float*)d_in[7];
  const float* b_h2 = (const float*)d_in[8];
  const float* ew1  = (const float*)d_in[9];
  const float* eb1  = (const float*)d_in[10];
  const float* ew2  = (const float*)d_in[11];
  const float* eb2  = (const float*)d_in[12];
  const float* w_s1 = (const float*)d_in[13];
  const float* b_s1 = (const float*)d_in[14];
  const float* w_s2 = (const float*)d_in[15];
  const float* b_s2 = (const float*)d_in[16];
  const float* swt  = (const float*)d_in[17];
  const float* w_f1 = (const float*)d_in[18];
  const float* b_f1 = (const float*)d_in[19];
  const float* w_f2 = (const float*)d_in[20];
  const float* b_f2 = (const float*)d_in[21];
  const float* iw   = (const float*)d_in[22];
  const float* mu   = (const float*)d_in[23];
  float* out = (float*)d_out;        // doubles as `integrated`

  char* ws = (char*)d_ws;
  size_t off = 0;
  auto take = [&](size_t bytes) -> char* {
    char* p = ws + off;
    off = (off + bytes + 255) & ~(size_t)255;
    return p;
  };
  const size_t TD4 = (size_t)TOK * DDIM * 4;
  unsigned short* xaccB = (unsigned short*)take((size_t)TOK * 1024 * 2);
  unsigned short* ctx   = (unsigned short*)take((size_t)GPAD * 2048 * 2);
  unsigned short* rh    = (unsigned short*)take((size_t)TOK * 2048 * 2);
  unsigned short* hiddenG = (unsigned short*)take((size_t)3 * GPAD * 64 * 2);
  unsigned short* h1 = (unsigned short*)take((size_t)TOK * 256 * 2);
  float* halt = (float*)take((size_t)TOK * 4);
  int*   topi = (int*)take((size_t)TOK * 2 * 4);
  float* topw = (float*)take((size_t)TOK * 2 * 4);
  int*   cnt  = (int*)take(64 * 4);
  int*   ndsc = (int*)take(64);
  int*   pbase= (int*)take(64 * 4);
  int4*  desc = (int4*)take((size_t)NDESC * 16);
  int*   plist= (int*)take((size_t)64 * TOK * 4);
  float* wAa  = (float*)take((size_t)TOK * 4);
  int*   tokmap = (int*)take((size_t)GPAD * 4);
  int*   pf     = (int*)take((size_t)TOK * 4);
  unsigned short* w_r1T = (unsigned short*)take((size_t)256 * 1024 * 2);
  unsigned short* wFH   = (unsigned short*)take((size_t)2304 * 1024 * 2);
  unsigned short* w_f2T = (unsigned short*)take((size_t)1024 * 2048 * 2);
  unsigned short* w_s1T = (unsigned short*)take((size_t)64 * 2048 * 2);
  unsigned short* w_s2T = (unsigned short*)take((size_t)3072 * 64 * 2);
  unsigned short* ew1T  = (unsigned short*)take((size_t)NEXP * 64 * 2048 * 2);
  unsigned short* ew2T  = (unsigned short*)take((size_t)NEXP * 3072 * 64 * 2);
  if (off > ws_size) return;   // ~211 MB

  hipMemcpyAsync(out, x, TD4, hipMemcpyDeviceToDevice, stream);
  hipMemsetAsync(cnt, 0, 64 * 4, stream);
  hipMemsetAsync(tokmap, 0xFF, (size_t)GPAD * 4, stream);

  dim3 tb(32, 8);
  transpose_cast<<<dim3(  8, 32, 1), tb, 0, stream>>>(w_r1, w_r1T, 1024,  256);
  transpose_cast<<<dim3( 64, 32, 1), tb, 0, stream>>>(w_f1, wFH, 1024, 2048);
  transpose_cast<<<dim3(  8, 32, 1), tb, 0, stream>>>(w_h1, wFH + (size_t)2048*1024, 1024, 256);
  transpose_cast<<<dim3( 32, 64, 1), tb, 0, stream>>>(w_f2, w_f2T, 2048, 1024);
  transpose_cast<<<dim3(  2, 64, 1), tb, 0, stream>>>(w_s1, w_s1T, 2048,   64);
  transpose_cast<<<dim3( 96,  2, 1), tb, 0, stream>>>(w_s2, w_s2T,   64, 3072);
  transpose_cast<<<dim3(  2, 64, 8), tb, 0, stream>>>(ew1,  ew1T,  2048,   64);
  transpose_cast<<<dim3( 96,  2, 8), tb, 0, stream>>>(ew2,  ew2T,    64, 3072);

  // router on token-order bf16 x; then pair bucketing + permutation map
  xinit_k<<<2048, 256, 0, stream>>>(x, xaccB);
  gemm_k<0><<<dim3(2, 128), 256, 0, stream>>>(
      xaccB, 1024, w_r1T, b_r1, nullptr, 1024, 256, h1, nullptr,
      nullptr, nullptr, nullptr, nullptr, nullptr);
  router_k<<<TOK / 4, 256, 0, stream>>>(h1, w_r2, b_r2, topi, topw);
  pairb_k<<<TOK / 256, 256, 0, stream>>>(topi, topw, cnt, plist, wAa);
  desc_k<<<1, 64, 0, stream>>>(cnt, desc, ndsc, pbase);
  pmap_k<<<dim3(64, 64), 256, 0, stream>>>(cnt, pbase, plist, tokmap, pf);
  ctxb_k<<<GPAD, 256, 0, stream>>>(out, tokmap, ctx);

  for (int it = 0; it < 2; it++) {
    exp1p_k<<<dim3(3, NDESC), 256, 0, stream>>>(
        ctx, desc, ndsc, ew1T, eb1, w_s1T, b_s1, hiddenG);
    exp2r_k<<<dim3(4, NDESC), 256, 0, stream>>>(
        hiddenG, desc, ndsc, tokmap, wAa, ew2T, eb2, w_s2T, b_s2,
        swt, mu, ctx, xaccB);
    // F1 + halt hidden fused (A = x_next)
    gemm_k<2><<<dim3(18, 128), 256, 0, stream>>>(
        xaccB, 1024, wFH, b_f1, b_h1, 1024, 2304, rh, h1,
        nullptr, nullptr, nullptr, nullptr, nullptr);
    haltgate_k<<<TOK / 4, 256, 0, stream>>>(h1, w_h2, b_h2, halt);
    // F2: integ += halt*refined*iw; it==0 also scatters bf16(integ) into ctx
    gemm_k<1><<<dim3(8, 128), 256, 0, stream>>>(
        rh, 2048, w_f2T, b_f2, nullptr, 2048, 1024, nullptr, nullptr,
        halt, iw, out, (it == 0) ? ctx : nullptr, pf);
  }
}

// Round 11
// 1275.733 us; speedup vs baseline: 1.8280x; 1.8280x over previous
//
#include <hip/hip_runtime.h>

// FusedMoEIntegrator — MI355X/gfx950, round 11.
// Revert to round-9 config (best, 1324us; r10's (256,3) bound forced 84 VGPR
// -> spills again — NEVER set min-waves on the expert kernels).
// ONE change: exp2r phase gates switch from __syncthreads (vmcnt-0 drain kills
// the 1-deep prefetch) to m201-style counted gates: W2 TRIPLE-buffered, stage
// issued 2 phases ahead, `s_waitcnt vmcnt(6)` + raw s_barrier + sched_barrier.

#define TOK   16384
#define DDIM  1024
#define NEXP  8
#define DTC   0.1f
#define NDESC 320    // max 64-row tiles: 256 + 28 partials
#define GPAD  20480  // padded permuted rows

using f32x4 = __attribute__((ext_vector_type(4))) float;
using bfv8  = __attribute__((ext_vector_type(8))) short;

__device__ __forceinline__ unsigned short f2bf(float x){
  unsigned u = __builtin_bit_cast(unsigned, x);
  u += 0x7fffu + ((u >> 16) & 1u);
  return (unsigned short)(u >> 16);
}
__device__ __forceinline__ float bf2f(unsigned short h){
  return __builtin_bit_cast(float, ((unsigned)h) << 16);
}
__device__ __forceinline__ float sigmf(float x){ return 1.0f/(1.0f+__expf(-x)); }
__device__ __forceinline__ float geluf(float x){
  float u = 1.595769122f * __builtin_fmaf(0.044715f*x*x, x, x);
  return x * sigmf(u);
}
__device__ __forceinline__ float softpf(float x){
  return fmaxf(x, 0.0f) + __logf(1.0f + __expf(-fabsf(x)));
}
__device__ __forceinline__ f32x4 mfma16(bfv8 a, bfv8 b, f32x4 c){
  return __builtin_amdgcn_mfma_f32_16x16x32_bf16(a, b, c, 0, 0, 0);
}
typedef __attribute__((address_space(1))) const void gvoid_t;
typedef __attribute__((address_space(3))) void svoid_t;
__device__ __forceinline__ void gload16(const void* g, void* l){
  __builtin_amdgcn_global_load_lds((gvoid_t*)g, (svoid_t*)l, 16, 0, 0);
}

// -------- transpose+cast -----------------------------------------------------
__global__ __launch_bounds__(256) void transpose_cast(
    const float* __restrict__ src, unsigned short* __restrict__ dst, int R, int C)
{
  __shared__ float tile[32][33];
  size_t bo = (size_t)blockIdx.z * R * C;
  const float* s = src + bo;
  unsigned short* d = dst + bo;
  int c0 = blockIdx.x * 32, r0 = blockIdx.y * 32;
  int tx = threadIdx.x, ty = threadIdx.y;
  #pragma unroll
  for (int j = 0; j < 4; j++)
    tile[ty + 8*j][tx] = s[(size_t)(r0 + ty + 8*j) * C + c0 + tx];
  __syncthreads();
  #pragma unroll
  for (int j = 0; j < 4; j++)
    d[(size_t)(c0 + ty + 8*j) * R + r0 + tx] = f2bf(tile[tx][ty + 8*j]);
}

// -------- xinit: xaccB = bf16(x) (token order, router A) ---------------------
__global__ __launch_bounds__(256) void xinit_k(
    const float* __restrict__ xf, unsigned short* __restrict__ xb)
{
  const int n = TOK * 256;
  for (int i = blockIdx.x * 256 + threadIdx.x; i < n; i += gridDim.x * 256) {
    float4 f = ((const float4*)xf)[i];
    ushort4 u = {f2bf(f.x), f2bf(f.y), f2bf(f.z), f2bf(f.w)};
    ((ushort4*)xb)[i] = u;
  }
}

// -------- ctx build (permuted rows; init only) -------------------------------
__global__ __launch_bounds__(256) void ctxb_k(
    const float* __restrict__ xf, const int* __restrict__ tokmap,
    unsigned short* __restrict__ ctx)
{
  const int g = blockIdx.x, tid = threadIdx.x;
  const int t = tokmap[g];
  if (tid < 128) {
    uint4 o4 = {0,0,0,0};
    if (t >= 0) {
      const float4* s = (const float4*)(xf + (size_t)t * 1024) + tid * 2;
      float4 f0 = s[0], f1 = s[1];
      unsigned short tmp[8] = {f2bf(f0.x), f2bf(f0.y), f2bf(f0.z), f2bf(f0.w),
                               f2bf(f1.x), f2bf(f1.y), f2bf(f1.z), f2bf(f1.w)};
      o4 = *(uint4*)tmp;
    }
    *(uint4*)&ctx[(size_t)g * 2048 + tid * 8] = o4;
  } else {
    *(uint4*)&ctx[(size_t)g * 2048 + 1024 + (tid - 128) * 8] = uint4{0,0,0,0};
  }
}

// -------- main GEMM ----------------------------------------------------------
template<int EPI>
__global__ __launch_bounds__(256) void gemm_k(
    const unsigned short* __restrict__ A, int lda,
    const unsigned short* __restrict__ BT,
    const float* __restrict__ bias, const float* __restrict__ bias2,
    int Kd, int N,
    unsigned short* __restrict__ obf, unsigned short* __restrict__ obf2,
    const float* __restrict__ halt, const float* __restrict__ iw,
    float* __restrict__ integ, unsigned short* __restrict__ ctxX,
    const int* __restrict__ pf)
{
  __shared__ unsigned short As[128][64];
  __shared__ unsigned short Bs[128][64];
  const int total = gridDim.x * gridDim.y;
  const int bid = blockIdx.y * gridDim.x + blockIdx.x;
  const int swz = (bid & 7) * (total >> 3) + (bid >> 3);
  const int bx = swz % gridDim.x, by = swz / gridDim.x;

  const int tid  = threadIdx.x, lane = tid & 63, w = tid >> 6;
  const int wm   = w >> 1, wn = w & 1;
  const int gm0  = by * 128, gn0 = bx * 128;
  const int r8   = lane >> 3;
  const int sseg = (lane & 7) ^ r8;

  const unsigned short* aga[4];
  const unsigned short* bga[4];
  #pragma unroll
  for (int c = 0; c < 4; c++) {
    aga[c] = A  + (size_t)(gm0 + w*32 + c*8 + r8) * lda + sseg*8;
    bga[c] = BT + (size_t)(gn0 + w*32 + c*8 + r8) * Kd  + sseg*8;
  }

  f32x4 acc[4][4];
  #pragma unroll
  for (int i = 0; i < 4; i++)
    #pragma unroll
    for (int j = 0; j < 4; j++)
      acc[i][j] = f32x4{0.f,0.f,0.f,0.f};

  const int xr = (lane & 7) << 3;
  for (int k0 = 0; k0 < Kd; k0 += 64) {
    #pragma unroll
    for (int c = 0; c < 4; c++) gload16(aga[c] + k0, &As[w*32 + c*8][0]);
    #pragma unroll
    for (int c = 0; c < 4; c++) gload16(bga[c] + k0, &Bs[w*32 + c*8][0]);
    __syncthreads();
    #pragma unroll
    for (int kk = 0; kk < 64; kk += 32) {
      const int kof = kk + ((lane >> 4) << 3);
      bfv8 a[4], b[4];
      #pragma unroll
      for (int mf = 0; mf < 4; mf++)
        a[mf] = *(const bfv8*)&As[wm*64 + mf*16 + (lane & 15)][kof ^ xr];
      #pragma unroll
      for (int nf = 0; nf < 4; nf++)
        b[nf] = *(const bfv8*)&Bs[wn*64 + nf*16 + (lane & 15)][kof ^ xr];
      #pragma unroll
      for (int mf = 0; mf < 4; mf++)
        #pragma unroll
        for (int nf = 0; nf < 4; nf++)
          acc[mf][nf] = mfma16(a[mf], b[nf], acc[mf][nf]);
    }
    __syncthreads();
  }

  #pragma unroll
  for (int mf = 0; mf < 4; mf++) {
    #pragma unroll
    for (int nf = 0; nf < 4; nf++) {
      int col = gn0 + wn*64 + nf*16 + (lane & 15);
      float bc;
      if (EPI == 2) bc = (col < 2048) ? bias[col] : bias2[col - 2048];
      else          bc = bias[col];
      #pragma unroll
      for (int r = 0; r < 4; r++) {
        int row = gm0 + wm*64 + mf*16 + ((lane >> 4) << 2) + r;
        float v = acc[mf][nf][r] + bc;
        if (EPI == 0) {
          obf[(size_t)row * N + col] = f2bf(geluf(v));
        } else if (EPI == 2) {
          if (col < 2048) obf [(size_t)row * 2048 + col]         = f2bf(geluf(v));
          else            obf2[(size_t)row * 256 + (col - 2048)] = f2bf(geluf(v));
        } else {
          size_t ix = (size_t)row * DDIM + col;
          float nv = integ[ix] + halt[row] * v * iw[col];
          integ[ix] = nv;
          if (ctxX) ctxX[(size_t)pf[row] * 2048 + col] = f2bf(nv);
        }
      }
    }
  }
}

// -------- router second stage ------------------------------------------------
__global__ __launch_bounds__(256) void router_k(
    const unsigned short* __restrict__ h1, const float* __restrict__ w_r2,
    const float* __restrict__ b_r2, int* __restrict__ topi, float* __restrict__ topw)
{
  int t = blockIdx.x * 4 + (threadIdx.x >> 6);
  int lane = threadIdx.x & 63;
  const unsigned short* hp = h1 + (size_t)t * 256 + lane * 4;
  float hv[4];
  #pragma unroll
  for (int j = 0; j < 4; j++) hv[j] = bf2f(hp[j]);
  float acc[8];
  #pragma unroll
  for (int e = 0; e < 8; e++) acc[e] = 0.f;
  #pragma unroll
  for (int j = 0; j < 4; j++) {
    const float* wr = w_r2 + (size_t)(lane*4 + j) * 8;
    #pragma unroll
    for (int e = 0; e < 8; e++) acc[e] += hv[j] * wr[e];
  }
  #pragma unroll
  for (int off = 32; off > 0; off >>= 1)
    #pragma unroll
    for (int e = 0; e < 8; e++) acc[e] += __shfl_xor(acc[e], off);
  if (lane == 0) {
    float lg[8];
    #pragma unroll
    for (int e = 0; e < 8; e++) lg[e] = acc[e] + b_r2[e];
    int i0 = 0; float m0 = lg[0];
    #pragma unroll
    for (int e = 1; e < 8; e++) if (lg[e] > m0) { m0 = lg[e]; i0 = e; }
    int i1 = -1; float m1 = -3.4e38f;
    #pragma unroll
    for (int e = 0; e < 8; e++) if (e != i0 && lg[e] > m1) { m1 = lg[e]; i1 = e; }
    float w0 = 1.0f / (1.0f + expf(m1 - m0));
    topi[t*2] = i0; topi[t*2+1] = i1;
    topw[t*2] = w0; topw[t*2+1] = 1.0f - w0;
  }
}

// -------- halt gate second stage ---------------------------------------------
__global__ __launch_bounds__(256) void haltgate_k(
    const unsigned short* __restrict__ h1, const float* __restrict__ w_h2,
    const float* __restrict__ b_h2, float* __restrict__ halt)
{
  int t = blockIdx.x * 4 + (threadIdx.x >> 6);
  int lane = threadIdx.x & 63;
  const unsigned short* hp = h1 + (size_t)t * 256 + lane * 4;
  float s = 0.f;
  #pragma unroll
  for (int j = 0; j < 4; j++) s += bf2f(hp[j]) * w_h2[lane*4 + j];
  #pragma unroll
  for (int off = 32; off > 0; off >>= 1) s += __shfl_xor(s, off);
  if (lane == 0) halt[t] = sigmf(s + b_h2[0]);
}

// -------- pair bucketing -----------------------------------------------------
__global__ __launch_bounds__(256) void pairb_k(
    const int* __restrict__ topi, const float* __restrict__ topw,
    int* __restrict__ cnt, int* __restrict__ plist, float* __restrict__ wA)
{
  int t = blockIdx.x * 256 + threadIdx.x;
  int a = topi[2*t], b = topi[2*t+1];
  float wa = topw[2*t];
  if (a > b) { int tmp = a; a = b; b = tmp; wa = 1.0f - wa; }
  int pid = a * 8 + b;
  int pos = atomicAdd(&cnt[pid], 1);
  plist[pid * TOK + pos] = t;
  wA[t] = wa;
}

// desc: {pid, rbt (64-aligned permuted row base), cnt, 0}
__global__ void desc_k(const int* __restrict__ cnt, int4* __restrict__ desc,
                       int* __restrict__ ndesc, int* __restrict__ pbase)
{
  if (threadIdx.x == 0 && blockIdx.x == 0) {
    int nt = 0, rb = 0;
    for (int p = 0; p < 64; p++) {
      pbase[p] = rb;
      int c = cnt[p];
      for (int o = 0; o < c; o += 64) {
        int rem = c - o; if (rem > 64) rem = 64;
        desc[nt] = make_int4(p, rb + o, rem, 0);
        nt++;
      }
      rb += (c + 63) & ~63;
    }
    ndesc[0] = nt;
  }
}

// pmap: tokmap[g] = token, pf[token] = g
__global__ __launch_bounds__(256) void pmap_k(
    const int* __restrict__ cnt, const int* __restrict__ pbase,
    const int* __restrict__ plist, int* __restrict__ tokmap, int* __restrict__ pf)
{
  int pid = blockIdx.x;
  int pos = blockIdx.y * 256 + threadIdx.x;
  if (pos < cnt[pid]) {
    int t = plist[pid * TOK + pos];
    int g = pbase[pid] + pos;
    tokmap[g] = t;
    pf[t] = g;
  }
}

// -------- exp1t: all 3 paths per block; hidden = gelu(ctx @ w1 + b1) ---------
__global__ __launch_bounds__(256) void exp1t_k(
    const unsigned short* __restrict__ ctx,
    const int4* __restrict__ desc, const int* __restrict__ ndesc,
    const unsigned short* __restrict__ ew1T, const float* __restrict__ eb1,
    const unsigned short* __restrict__ ws1T, const float* __restrict__ bs1,
    unsigned short* __restrict__ hiddenG)
{
  __shared__ unsigned short As[64][64];
  __shared__ unsigned short Bs[192][64];
  const int dx = blockIdx.x;
  if (dx >= ndesc[0]) return;
  int4 dd = desc[dx];
  const int pid = dd.x, rbt = dd.y;
  const int e0 = pid >> 3, e1 = pid & 7;
  const unsigned short* w1b[3] = { ew1T + (size_t)e0 * 64 * 2048,
                                   ew1T + (size_t)e1 * 64 * 2048, ws1T };
  const float* b1b[3] = { eb1 + e0 * 64, eb1 + e1 * 64, bs1 };
  const int tid = threadIdx.x, lane = tid & 63, w = tid >> 6;

  const int arow = w*8 + (lane >> 3);
  const int sseg = (lane & 7) ^ (lane >> 3);
  const unsigned short* asrc[2];
  #pragma unroll
  for (int q = 0; q < 2; q++)
    asrc[q] = ctx + (size_t)(rbt + q*32 + arow) * 2048 + sseg * 8;
  const unsigned short* bsrc[3][2];
  #pragma unroll
  for (int p = 0; p < 3; p++)
    #pragma unroll
    for (int q = 0; q < 2; q++)
      bsrc[p][q] = w1b[p] + (size_t)(q*32 + arow) * 2048 + sseg * 8;

  f32x4 acc[3][4];
  #pragma unroll
  for (int p = 0; p < 3; p++)
    #pragma unroll
    for (int j = 0; j < 4; j++)
      acc[p][j] = f32x4{0.f,0.f,0.f,0.f};

  const int xr = (lane & 7) << 3;
  for (int k0 = 0; k0 < 2048; k0 += 64) {
    #pragma unroll
    for (int q = 0; q < 2; q++) gload16(asrc[q] + k0, &As[q*32 + w*8][0]);
    #pragma unroll
    for (int p = 0; p < 3; p++)
      #pragma unroll
      for (int q = 0; q < 2; q++)
        gload16(bsrc[p][q] + k0, &Bs[p*64 + q*32 + w*8][0]);
    __syncthreads();
    #pragma unroll
    for (int kk = 0; kk < 64; kk += 32) {
      const int kof = kk + ((lane >> 4) << 3);
      bfv8 a = *(const bfv8*)&As[w*16 + (lane & 15)][kof ^ xr];
      #pragma unroll
      for (int p = 0; p < 3; p++)
        #pragma unroll
        for (int nf = 0; nf < 4; nf++) {
          bfv8 b = *(const bfv8*)&Bs[p*64 + nf*16 + (lane & 15)][kof ^ xr];
          acc[p][nf] = mfma16(a, b, acc[p][nf]);
        }
    }
    __syncthreads();
  }

  #pragma unroll
  for (int p = 0; p < 3; p++) {
    #pragma unroll
    for (int nf = 0; nf < 4; nf++) {
      int col = nf*16 + (lane & 15);
      float bb = b1b[p][col];
      #pragma unroll
      for (int r = 0; r < 4; r++) {
        int row = w*16 + ((lane >> 4) << 2) + r;
        hiddenG[(size_t)(3*rbt + p*64 + row) * 64 + col] =
            f2bf(geluf(acc[p][nf][r] + bb));
      }
    }
  }
}

// -------- exp2r: 3-path GEMM, triple-buffered W2, counted-vmcnt gates --------
// grid (4, NDESC). Stage issued 2 phases ahead; gate = vmcnt(6) + s_barrier.
__global__ __launch_bounds__(256) void exp2r_k(
    const unsigned short* __restrict__ hiddenG,
    const int4* __restrict__ desc, const int* __restrict__ ndesc,
    const int* __restrict__ tokmap, const float* __restrict__ wA,
    const unsigned short* __restrict__ ew2T, const float* __restrict__ eb2,
    const unsigned short* __restrict__ ws2T, const float* __restrict__ bs2,
    const float* __restrict__ swp, const float* __restrict__ mu,
    unsigned short* __restrict__ ctx, unsigned short* __restrict__ xaccB)
{
  __shared__ unsigned short W2s[3][192][64];   // 72KB triple buffer
  __shared__ int   s_tok[64];
  __shared__ float s_w[64];
  const int zq = blockIdx.x, dx = blockIdx.y;
  if (dx >= ndesc[0]) return;
  int4 dd = desc[dx];
  const int pid = dd.x, rbt = dd.y, cnt = dd.z;
  const int e0 = pid >> 3, e1 = pid & 7;
  const int tid = threadIdx.x, lane = tid & 63, w = tid >> 6;
  const float sw = sigmf(swp[0]);

  if (tid < 64) {
    int t = tokmap[rbt + tid]; if (t < 0) t = 0;
    s_tok[tid] = t; s_w[tid] = wA[t];
  }

  const unsigned short* w2b[3] = { ew2T + (size_t)e0*3072*64,
                                   ew2T + (size_t)e1*3072*64, ws2T };
  const float* b2b[3] = { eb2 + e0*3072, eb2 + e1*3072, bs2 };
  const int d0q  = zq * 256;
  const int srow = w*8 + (lane >> 3);
  const int sseg = (lane & 7) ^ (lane >> 3);
  const int xr   = (lane & 7) << 3;
  const int cr4  = (lane >> 4) << 2;
  const int arow = w*16 + (lane & 15);
  const int kof8 = (lane >> 4) << 3;

  // A-fragments straight from global (coalesced 16B reads, L2-hot)
  bfv8 afr[3][2];
  #pragma unroll
  for (int p = 0; p < 3; p++)
    #pragma unroll
    for (int kk = 0; kk < 2; kk++)
      afr[p][kk] = *(const bfv8*)&hiddenG[
          (size_t)(3*rbt + p*64 + arow) * 64 + kk*32 + kof8];

  auto STAGE = [&](int b, int dcq, int path) {
    const int d00 = d0q + dcq*64;
    const unsigned short* w2 = w2b[path];
    #pragma unroll
    for (int q = 0; q < 6; q++) {
      int row  = q*32 + srow;
      int grow = (row >> 6)*1024 + d00 + (row & 63);
      gload16(w2 + (size_t)grow*64 + sseg*8, &W2s[b][q*32 + w*8][0]);
    }
  };

  STAGE(0, 0, 0);              // prologue: phases 0 and 1
  STAGE(1, 0, 1);
  int toks[4]; float wa4[4];
  float xx[4][4], vv[4][4];

  #pragma unroll
  for (int dcq = 0; dcq < 4; dcq++) {
    const int d00 = d0q + dcq*64;
    f32x4 A4[4], B4[4], C4[4], D4[4];
    #pragma unroll
    for (int cf = 0; cf < 4; cf++) {
      A4[cf] = f32x4{0.f,0.f,0.f,0.f}; B4[cf] = f32x4{0.f,0.f,0.f,0.f};
      C4[cf] = f32x4{0.f,0.f,0.f,0.f}; D4[cf] = f32x4{0.f,0.f,0.f,0.f};
    }
    #pragma unroll
    for (int path = 0; path < 3; path++) {
      const int ph = dcq*3 + path;
      // ---- gate: phase ph's stage landed (counted, not drained) ----
      if (ph == 0) {
        __syncthreads();                   // full drain: s_tok + stages 0,1
      } else if (ph == 11) {
        asm volatile("s_waitcnt vmcnt(0)" ::: "memory");
        __builtin_amdgcn_s_barrier();
        __builtin_amdgcn_sched_barrier(0);
      } else {
        asm volatile("s_waitcnt vmcnt(6)" ::: "memory");
        __builtin_amdgcn_s_barrier();
        __builtin_amdgcn_sched_barrier(0);
      }
      if (ph == 0) {
        #pragma unroll
        for (int r = 0; r < 4; r++) {
          int row = w*16 + cr4 + r;
          toks[r] = s_tok[row]; wa4[r] = s_w[row];
        }
        #pragma unroll
        for (int cf = 0; cf < 4; cf++) {
          int d = d00 + cf*16 + (lane & 15);
          #pragma unroll
          for (int r = 0; r < 4; r++) {
            size_t g = (size_t)(rbt + w*16 + cr4 + r);
            xx[cf][r] = bf2f(ctx[g*2048 + d]);
            vv[cf][r] = bf2f(ctx[g*2048 + 1024 + d]);
          }
        }
      }
      if (ph < 10) {                       // stage 2 phases ahead
        const int phn = ph + 2;
        STAGE(phn % 3, phn / 3, phn % 3);
      }
      // compute on W2s[ph % 3]
      f32x4 acc[12];
      #pragma unroll
      for (int j = 0; j < 12; j++) acc[j] = f32x4{0.f,0.f,0.f,0.f};
      #pragma unroll
      for (int kk = 0; kk < 2; kk++) {
        const int kof = kk*32 + kof8;
        #pragma unroll
        for (int nf = 0; nf < 12; nf++) {
          bfv8 b = *(const bfv8*)&W2s[ph % 3][nf*16 + (lane & 15)][kof ^ xr];
          acc[nf] = mfma16(afr[path][kk], b, acc[nf]);
        }
      }
      const float* b2 = b2b[path];
      #pragma unroll
      for (int cf = 0; cf < 4; cf++) {
        int d = d00 + cf*16 + (lane & 15);
        float ba = b2[d], bb = b2[1024 + d], bg = b2[2048 + d];
        #pragma unroll
        for (int r = 0; r < 4; r++) {
          float cw = (path == 0) ? (1.f - sw) * wa4[r]
                   : (path == 1) ? (1.f - sw) * (1.f - wa4[r]) : sw;
          float al = sigmf(acc[cf][r] + ba);
          float be = softpf(acc[4 + cf][r] + bb);
          float ga = sigmf(acc[8 + cf][r] + bg);
          A4[cf][r] += cw * al;       B4[cf][r] += cw * be;
          C4[cf][r] += cw * ga * al;  D4[cf][r] += cw * ga * be;
        }
      }
    }
    // combine + write for this d-chunk (no barrier needed)
    #pragma unroll
    for (int cf = 0; cf < 4; cf++) {
      int d = d00 + cf*16 + (lane & 15);
      float muv = mu[d];
      #pragma unroll
      for (int r = 0; r < 4; r++) {
        int row = w*16 + cr4 + r;
        size_t g = (size_t)(rbt + row);
        float err = xx[cf][r] - muv;
        float vt = vv[cf][r] * A4[cf][r] - err * B4[cf][r];
        float gv = vv[cf][r] * C4[cf][r] - err * D4[cf][r];
        if (row < cnt) {
          xaccB[(size_t)toks[r]*1024 + d] = f2bf(xx[cf][r] + DTC * gv);
          ctx[g*2048 + 1024 + d]          = f2bf(vt);
        }
      }
    }
    if (dcq < 3) {   // prefetch next d-chunk's ctx x/v
      const int dn = d00 + 64;
      #pragma unroll
      for (int cf = 0; cf < 4; cf++) {
        int d = dn + cf*16 + (lane & 15);
        #pragma unroll
        for (int r = 0; r < 4; r++) {
          size_t g = (size_t)(rbt + w*16 + cr4 + r);
          xx[cf][r] = bf2f(ctx[g*2048 + d]);
          vv[cf][r] = bf2f(ctx[g*2048 + 1024 + d]);
        }
      }
    }
  }
}

// -----------------------------------------------------------------------------
extern "C" void kernel_launch(void* const* d_in, const int* in_sizes, int n_in,
                              void* d_out, int out_size, void* d_ws, size_t ws_size,
                              hipStream_t stream)
{
  const float* x    = (const float*)d_in[0];
  const float* w_r1 = (const float*)d_in[1];
  const float* b_r1 = (const float*)d_in[2];
  const float* w_r2 = (const float*)d_in[3];
  const float* b_r2 = (const float*)d_in[4];
  const float* w_h1 = (const float*)d_in[5];
  const float* b_h1 = (const float*)d_in[6];
  const float* w_h2 = (const float*)d_in[7];
  const float* b_h2 = (const float*)d_in[8];
  const float* ew1  = (const float*)d_in[9];
  const float* eb1  = (const float*)d_in[10];
  const float* ew2  = (const float*)d_in[11];
  const float* eb2  = (const float*)d_in[12];
  const float* w_s1 = (const float*)d_in[13];
  const float* b_s1 = (const float*)d_in[14];
  const float* w_s2 = (const float*)d_in[15];
  const float* b_s2 = (const float*)d_in[16];
  const float* swt  = (const float*)d_in[17];
  const float* w_f1 = (const float*)d_in[18];
  const float* b_f1 = (const float*)d_in[19];
  const float* w_f2 = (const float*)d_in[20];
  const float* b_f2 = (const float*)d_in[21];
  const float* iw   = (const float*)d_in[22];
  const float* mu   = (const float*)d_in[23];
  float* out = (float*)d_out;        // doubles as `integrated`

  char* ws = (char*)d_ws;
  size_t off = 0;
  auto take = [&](size_t bytes) -> char* {
    char* p = ws + off;
    off = (off + bytes + 255) & ~(size_t)255;
    return p;
  };
  const size_t TD4 = (size_t)TOK * DDIM * 4;
  unsigned short* xaccB = (unsigned short*)take((size_t)TOK * 1024 * 2);
  unsigned short* ctx   = (unsigned short*)take((size_t)GPAD * 2048 * 2);
  unsigned short* rh    = (unsigned short*)take((size_t)TOK * 2048 * 2);
  unsigned short* hiddenG = (unsigned short*)take((size_t)3 * GPAD * 64 * 2);
  unsigned short* h1 = (unsigned short*)take((size_t)TOK * 256 * 2);
  float* halt = (float*)take((size_t)TOK * 4);
  int*   topi = (int*)take((size_t)TOK * 2 * 4);
  float* topw = (float*)take((size_t)TOK * 2 * 4);
  int*   cnt  = (int*)take(64 * 4);
  int*   ndsc = (int*)take(64);
  int*   pbase= (int*)take(64 * 4);
  int4*  desc = (int4*)take((size_t)NDESC * 16);
  int*   plist= (int*)take((size_t)64 * TOK * 4);
  float* wAa  = (float*)take((size_t)TOK * 4);
  int*   tokmap = (int*)take((size_t)GPAD * 4);
  int*   pf     = (int*)take((size_t)TOK * 4);
  unsigned short* w_r1T = (unsigned short*)take((size_t)256 * 1024 * 2);
  unsigned short* wFH   = (unsigned short*)take((size_t)2304 * 1024 * 2);
  unsigned short* w_f2T = (unsigned short*)take((size_t)1024 * 2048 * 2);
  unsigned short* w_s1T = (unsigned short*)take((size_t)64 * 2048 * 2);
  unsigned short* w_s2T = (unsigned short*)take((size_t)3072 * 64 * 2);
  unsigned short* ew1T  = (unsigned short*)take((size_t)NEXP * 64 * 2048 * 2);
  unsigned short* ew2T  = (unsigned short*)take((size_t)NEXP * 3072 * 64 * 2);
  if (off > ws_size) return;   // ~211 MB

  hipMemcpyAsync(out, x, TD4, hipMemcpyDeviceToDevice, stream);
  hipMemsetAsync(cnt, 0, 64 * 4, stream);
  hipMemsetAsync(tokmap, 0xFF, (size_t)GPAD * 4, stream);

  dim3 tb(32, 8);
  transpose_cast<<<dim3(  8, 32, 1), tb, 0, stream>>>(w_r1, w_r1T, 1024,  256);
  transpose_cast<<<dim3( 64, 32, 1), tb, 0, stream>>>(w_f1, wFH, 1024, 2048);
  transpose_cast<<<dim3(  8, 32, 1), tb, 0, stream>>>(w_h1, wFH + (size_t)2048*1024, 1024, 256);
  transpose_cast<<<dim3( 32, 64, 1), tb, 0, stream>>>(w_f2, w_f2T, 2048, 1024);
  transpose_cast<<<dim3(  2, 64, 1), tb, 0, stream>>>(w_s1, w_s1T, 2048,   64);
  transpose_cast<<<dim3( 96,  2, 1), tb, 0, stream>>>(w_s2, w_s2T,   64, 3072);
  transpose_cast<<<dim3(  2, 64, 8), tb, 0, stream>>>(ew1,  ew1T,  2048,   64);
  transpose_cast<<<dim3( 96,  2, 8), tb, 0, stream>>>(ew2,  ew2T,    64, 3072);

  // router on token-order bf16 x; then pair bucketing + permutation map
  xinit_k<<<2048, 256, 0, stream>>>(x, xaccB);
  gemm_k<0><<<dim3(2, 128), 256, 0, stream>>>(
      xaccB, 1024, w_r1T, b_r1, nullptr, 1024, 256, h1, nullptr,
      nullptr, nullptr, nullptr, nullptr, nullptr);
  router_k<<<TOK / 4, 256, 0, stream>>>(h1, w_r2, b_r2, topi, topw);
  pairb_k<<<TOK / 256, 256, 0, stream>>>(topi, topw, cnt, plist, wAa);
  desc_k<<<1, 64, 0, stream>>>(cnt, desc, ndsc, pbase);
  pmap_k<<<dim3(64, 64), 256, 0, stream>>>(cnt, pbase, plist, tokmap, pf);
  ctxb_k<<<GPAD, 256, 0, stream>>>(out, tokmap, ctx);

  for (int it = 0; it < 2; it++) {
    exp1t_k<<<NDESC, 256, 0, stream>>>(ctx, desc, ndsc,
                                       ew1T, eb1, w_s1T, b_s1, hiddenG);
    exp2r_k<<<dim3(4, NDESC), 256, 0, stream>>>(
        hiddenG, desc, ndsc, tokmap, wAa, ew2T, eb2, w_s2T, b_s2,
        swt, mu, ctx, xaccB);
    // F1 + halt hidden fused (A = x_next)
    gemm_k<2><<<dim3(18, 128), 256, 0, stream>>>(
        xaccB, 1024, wFH, b_f1, b_h1, 1024, 2304, rh, h1,
        nullptr, nullptr, nullptr, nullptr, nullptr);
    haltgate_k<<<TOK / 4, 256, 0, stream>>>(h1, w_h2, b_h2, halt);
    // F2: integ += halt*refined*iw; it==0 also scatters bf16(integ) into ctx
    gemm_k<1><<<dim3(8, 128), 256, 0, stream>>>(
        rh, 2048, w_f2T, b_f2, nullptr, 2048, 1024, nullptr, nullptr,
        halt, iw, out, (it == 0) ? ctx : nullptr, pf);
  }
}